// Round 13
// baseline (182.771 us; speedup 1.0000x reference)
//
#include <hip/hip_runtime.h>
#include <hip/hip_bf16.h>
#include <stdint.h>

static constexpr int Bsz = 1024;
static constexpr int TT  = 256;
static constexpr int FF  = 124;
static constexpr int HH  = 64;
static constexpr int GG  = 256;   // 4*H
static constexpr int BB  = 16;    // batch rows per block
static constexpr int C_OFF = Bsz * 8;
static constexpr int H_OFF = C_OFF + Bsz * HH;

// packed-weight workspace layout (uint16_t units)
static constexpr int WXH_U16 = 24 * 256 * 8;      // Wx/Wh frags
static constexpr int W1P_U16 = 256 * 4096;        // W1 frags, 256 blocks x 8KB
static constexpr size_t WS_NEED = (size_t)(WXH_U16 + W1P_U16) * 2;  // ~2.1 MB

// LDS pool layout (bytes)
static constexpr int XS0 = 0;        // 8 slots x 8192 (f32 xs, swizzled; W2 aliases after loop)
static constexpr int BX0 = 65536;    // 4 slots x 4096 (bf16 xs, MFMA-frag layout)
static constexpr int HB0 = 81920;    // 2 x 2048      (bf16 h, swizzled)
static constexpr int MA0 = 86016;    // 16*65*4
static constexpr int MB0 = 90176;    // 16*65*4
static constexpr int POOLSZ = 94336;

typedef __attribute__((ext_vector_type(8))) short bf16x8;
typedef __attribute__((ext_vector_type(4))) float f32x4;

#define MFMA16 __builtin_amdgcn_mfma_f32_16x16x32_bf16

__device__ __forceinline__ uint16_t f2bf(float x) {
  union { float f; uint32_t u; } v; v.f = x;
  return (uint16_t)((v.u + 0x7FFFu + ((v.u >> 16) & 1u)) >> 16);
}
__device__ __forceinline__ uint32_t cvtpk(float lo, float hi) {
  uint32_t r;
  asm("v_cvt_pk_bf16_f32 %0, %1, %2" : "=v"(r) : "v"(lo), "v"(hi));
  return r;
}
__device__ __forceinline__ uint16_t bf1(float x) { return (uint16_t)cvtpk(x, x); }
__device__ __forceinline__ float fsig(float x) {
  return __builtin_amdgcn_rcpf(1.0f + __builtin_amdgcn_exp2f(-1.4426950408889634f * x));
}
__device__ __forceinline__ float ftanh(float x) {
  float e = __builtin_amdgcn_exp2f(-2.8853900817779268f * x);
  return (1.0f - e) * __builtin_amdgcn_rcpf(1.0f + e);
}
__device__ __forceinline__ bf16x8 cvt8(float4 a, float4 b) {
  union { uint32_t u[4]; bf16x8 v; } r;
  r.u[0] = cvtpk(a.x, a.y); r.u[1] = cvtpk(a.z, a.w);
  r.u[2] = cvtpk(b.x, b.y); r.u[3] = cvtpk(b.z, b.w);
  return r.v;
}
__device__ __forceinline__ void dma16(const void* g, void* l) {
  __builtin_amdgcn_global_load_lds(
      (const __attribute__((address_space(1))) uint32_t*)g,
      (__attribute__((address_space(3))) uint32_t*)l, 16, 0, 0);
}

// ---------------- pre-pass: pack Wx/Wh/W1 into bf16 fragment order ----------------
__global__ __launch_bounds__(256) void pack_weights(
    const float* __restrict__ Wx, const float* __restrict__ Wh,
    const float* __restrict__ W1, uint16_t* __restrict__ wsp)
{
  const int c = blockIdx.x * 256 + threadIdx.x;
  uint16_t v[8];
  size_t dst;
  if (c < 6144) {                       // Wx/Wh frags: [f 0..23][tid 0..255][8]
    const int f = c >> 8, tid = c & 255;
    const int w = tid >> 6, l = tid & 63;
    const int kgl = (l >> 4) * 8, r16 = l & 15;
    if (f < 16) {
      const int g = f >> 2, kf = f & 3;
      const int col = g * 64 + w * 16 + r16;
#pragma unroll
      for (int j = 0; j < 8; ++j) v[j] = f2bf(Wx[(size_t)(kf * 32 + kgl + j) * GG + col]);
    } else {
      const int g = (f - 16) >> 1, kf = (f - 16) & 1;
      const int col = g * 64 + w * 16 + r16;
#pragma unroll
      for (int j = 0; j < 8; ++j) v[j] = f2bf(Wh[(size_t)(kf * 32 + kgl + j) * GG + col]);
    }
    dst = (size_t)c * 8;
  } else if (c < 6144 + 131072) {       // W1 frags: [t][w][half][l][8]
    const int cc = c - 6144;
    const int t = cc >> 9, r = cc & 511;
    const int w = r >> 7, half = (r >> 6) & 1, l = r & 63;
    const int row0 = t * 64 + half * 32 + (l >> 4) * 8;
    const int col = w * 16 + (l & 15);
#pragma unroll
    for (int j = 0; j < 8; ++j) v[j] = f2bf(W1[(size_t)(row0 + j) * 64 + col]);
    dst = (size_t)WXH_U16 + (size_t)cc * 8;
  } else return;
  uint4 pk;
  pk.x = (uint32_t)v[0] | ((uint32_t)v[1] << 16);
  pk.y = (uint32_t)v[2] | ((uint32_t)v[3] << 16);
  pk.z = (uint32_t)v[4] | ((uint32_t)v[5] << 16);
  pk.w = (uint32_t)v[6] | ((uint32_t)v[7] << 16);
  *(uint4*)(wsp + dst) = pk;
}

// ---------------- main kernel: 4 consumers + 4 converters (who also own W1) ----------------
// DMA invariants as R8/R12.  NEW in R13: the W1 stream (global loads, wacc MFMAs,
// epilogue tail) lives on the CONVERTER waves, with a parity double-buffer:
// period t uses cw[t&1] (= block t-1, loaded at t-1) and loads block t into
// cw[(t+1)&1] -> no load is consumed in its issue period (full-period slack).
// Consumers do only: bxs/h ds_reads -> 24 gate MFMAs -> elementwise -> h write.

#define PER_CVT(PRT, U, CWUa, CWUb, CWNa, CWNb) { \
  asm volatile("s_waitcnt vmcnt(6)" ::: "memory"); \
  { const uint16_t* w1p = wsp + (size_t)WXH_U16 + ((size_t)(PRT) * 512 + pw * 128 + l) * 8; \
    CWNa = *(const bf16x8*)(w1p); \
    CWNb = *(const bf16x8*)(w1p + 512); } \
  if ((PRT) + 2 < TT) { \
    const char* xb = pool + (((U) + 2) & 7) * 8192; \
    float4 ya = *(const float4*)(xb + offxA); \
    float4 yb = *(const float4*)(xb + offxB); \
    bf16x8 bv = cvt8(ya, yb); \
    *(bf16x8*)(pool + BX0 + (((U) + 2) & 3) * 4096 + row16 * 256 + \
               (((pw * 4 + kg) << 4) ^ swz)) = bv; \
  } \
  { char* ld = pool + (((U) + 6) & 7) * 8192 + pw * 2048; \
    dma16(gsrc0, ld); dma16(gsrc1, ld + 1024); } \
  if ((PRT) + 7 < TT) { gsrc0 += inc0; gsrc1 += inc1; } \
  { const char* hb = pool + HB0 + ((U) & 1) * 2048; \
    bf16x8 ah0 = *(const bf16x8*)(hb + row16 * 128 + (((0 + kg) << 4) ^ swz)); \
    bf16x8 ah1 = *(const bf16x8*)(hb + row16 * 128 + (((4 + kg) << 4) ^ swz)); \
    wacc = MFMA16(ah0, CWUa, wacc, 0, 0, 0); \
    wacc = MFMA16(ah1, CWUb, wacc, 0, 0, 0); } }

#define PER_CONS(PRT, U) { \
  const char* bx = pool + BX0 + ((U) & 3) * 4096; \
  bf16x8 ax0 = *(const bf16x8*)(bx + row16 * 256 + (((0 * 4 + kg) << 4) ^ swz)); \
  bf16x8 ax1 = *(const bf16x8*)(bx + row16 * 256 + (((1 * 4 + kg) << 4) ^ swz)); \
  bf16x8 ax2 = *(const bf16x8*)(bx + row16 * 256 + (((2 * 4 + kg) << 4) ^ swz)); \
  bf16x8 ax3 = *(const bf16x8*)(bx + row16 * 256 + (((3 * 4 + kg) << 4) ^ swz)); \
  const char* hb = pool + HB0 + ((U) & 1) * 2048; \
  bf16x8 ah0 = *(const bf16x8*)(hb + row16 * 128 + (((0 + kg) << 4) ^ swz)); \
  bf16x8 ah1 = *(const bf16x8*)(hb + row16 * 128 + (((4 + kg) << 4) ^ swz)); \
  f32x4 g0 = {bias4[0], bias4[0], bias4[0], bias4[0]}; \
  f32x4 g1 = {bias4[1], bias4[1], bias4[1], bias4[1]}; \
  f32x4 g2 = {bias4[2], bias4[2], bias4[2], bias4[2]}; \
  f32x4 g3 = {bias4[3], bias4[3], bias4[3], bias4[3]}; \
  g0 = MFMA16(ax0, bwx[0][0], g0, 0, 0, 0); \
  g1 = MFMA16(ax0, bwx[1][0], g1, 0, 0, 0); \
  g2 = MFMA16(ax0, bwx[2][0], g2, 0, 0, 0); \
  g3 = MFMA16(ax0, bwx[3][0], g3, 0, 0, 0); \
  g0 = MFMA16(ax1, bwx[0][1], g0, 0, 0, 0); \
  g1 = MFMA16(ax1, bwx[1][1], g1, 0, 0, 0); \
  g2 = MFMA16(ax1, bwx[2][1], g2, 0, 0, 0); \
  g3 = MFMA16(ax1, bwx[3][1], g3, 0, 0, 0); \
  g0 = MFMA16(ax2, bwx[0][2], g0, 0, 0, 0); \
  g1 = MFMA16(ax2, bwx[1][2], g1, 0, 0, 0); \
  g2 = MFMA16(ax2, bwx[2][2], g2, 0, 0, 0); \
  g3 = MFMA16(ax2, bwx[3][2], g3, 0, 0, 0); \
  g0 = MFMA16(ax3, bwx[0][3], g0, 0, 0, 0); \
  g1 = MFMA16(ax3, bwx[1][3], g1, 0, 0, 0); \
  g2 = MFMA16(ax3, bwx[2][3], g2, 0, 0, 0); \
  g3 = MFMA16(ax3, bwx[3][3], g3, 0, 0, 0); \
  g0 = MFMA16(ah0, bwh[0][0], g0, 0, 0, 0); \
  g1 = MFMA16(ah0, bwh[1][0], g1, 0, 0, 0); \
  g2 = MFMA16(ah0, bwh[2][0], g2, 0, 0, 0); \
  g3 = MFMA16(ah0, bwh[3][0], g3, 0, 0, 0); \
  g0 = MFMA16(ah1, bwh[0][1], g0, 0, 0, 0); \
  g1 = MFMA16(ah1, bwh[1][1], g1, 0, 0, 0); \
  g2 = MFMA16(ah1, bwh[2][1], g2, 0, 0, 0); \
  g3 = MFMA16(ah1, bwh[3][1], g3, 0, 0, 0); \
  char* hw = pool + HB0 + (((U) & 1) ^ 1) * 2048; \
  _Pragma("unroll") \
  for (int jj = 0; jj < 4; ++jj) { \
    float i_ = fsig(g0[jj]); \
    float f_ = fsig(g1[jj]); \
    float gv = ftanh(g2[jj]); \
    float o_ = fsig(g3[jj]); \
    float cn = f_ * cacc[jj] + i_ * gv; \
    cacc[jj] = cn; \
    float hv = o_ * ftanh(cn); \
    const int row = kg * 4 + jj; \
    *(uint16_t*)(hw + row * 128 + (((kcol >> 3) << 4) ^ ((row & 7) << 4)) + (kcol & 7) * 2) = bf1(hv); \
  } }

#define PERIOD(PRT, U, CWUa, CWUb, CWNa, CWNb) { \
  if (w < 4) { PER_CONS(PRT, U) } else { PER_CVT(PRT, U, CWUa, CWUb, CWNa, CWNb) } \
  asm volatile("s_waitcnt lgkmcnt(0)\n\ts_barrier" ::: "memory"); }

// 512 threads = 8 waves = 2 waves/EU at 1 block/CU.  (512,2) -> VGPR cap 256
// (the ONLY declaration proven to unlock the allocator; defaults/(768,3) spill).
__global__ __launch_bounds__(512, 2)
void actor_sx(
    const float* __restrict__ x,  const float* __restrict__ pa,
    const float* __restrict__ bg, const uint16_t* __restrict__ wsp,
    const float* __restrict__ b1, const float* __restrict__ W2,
    const float* __restrict__ b2, const float* __restrict__ W3,
    const float* __restrict__ b3, float* __restrict__ out)
{
  __shared__ __align__(16) char pool[POOLSZ];

  const int tid   = threadIdx.x;
  const int w     = tid >> 6;     // 0..3 consumers (gate-col slice), 4..7 converters (+W1)
  const int cs    = w & 3;
  const int pw    = w & 3;
  const int l     = tid & 63;
  const int row16 = l & 15;
  const int kg    = l >> 4;
  const int b0    = blockIdx.x * BB;
  const int swz   = (row16 & 7) << 4;
  const int kcol  = cs * 16 + row16;

  if (w < 4) __builtin_amdgcn_s_setprio(1);

  // ---- role state ----
  bf16x8 bwx[4][4];     // consumers (loop-spanning)
  bf16x8 bwh[4][2];     // consumers
  float  bias4[4];      // consumers
  bf16x8 cwa0 = {}, cwb0 = {}, cwa1 = {}, cwb1 = {};   // converters: W1 parity dbuf
  float  cacc[4] = {0.f, 0.f, 0.f, 0.f};               // consumers
  f32x4  wacc = {0.f, 0.f, 0.f, 0.f};                  // converters

  // converter read offsets: this wave's K-quarter (kf = pw) of the f32 xs tile
  int offxA, offxB;
  {
    const int rb = row16 * 512, r7 = row16 & 7;
    offxA = rb + (((pw * 8 + kg * 2 + 0) ^ r7) << 4);
    offxB = rb + (((pw * 8 + kg * 2 + 1) ^ r7) << 4);
  }
  // xs DMA source pointers (per-lane swizzled global addresses) — R8-proven
  const char* gsrc0; const char* gsrc1; int inc0 = 0, inc1 = 0;
  {
#define GSRC(j, G, INC) { \
    const int d = pw * 2 + (j); \
    const int row = d * 2 + (l >> 5); \
    const int c_swz = l & 31; \
    const int c_or = c_swz ^ (row & 7); \
    const size_t rb_ = (size_t)(b0 + row) * TT; \
    if (c_or == 31) { G = (const char*)(pa + rb_ * 4); INC = 16; } \
    else { G = (const char*)(x + rb_ * FF + c_or * 4); INC = FF * 4; } }
    GSRC(0, gsrc0, inc0)
    GSRC(1, gsrc1, inc1)
#undef GSRC
  }

  if (w >= 4) {
    // prologue DMAs: xs(0..5) into slots 0..5 (12 issues, pair order per t)
#pragma unroll
    for (int s = 0; s < 6; ++s) {
      char* ld = pool + s * 8192 + pw * 2048;
      dma16(gsrc0, ld); dma16(gsrc1, ld + 1024);
      gsrc0 += inc0; gsrc1 += inc1;   // ends at t = 6
    }
    // W1 parity-buffer init: cw*0 <- block 0 (used at period 0 with h(-1)=0 -> +0)
    const uint16_t* w1p = wsp + (size_t)WXH_U16 + ((size_t)pw * 128 + l) * 8;
    cwa0 = *(const bf16x8*)(w1p);
    cwb0 = *(const bf16x8*)(w1p + 512);
  } else {
#pragma unroll
    for (int g = 0; g < 4; ++g) {
#pragma unroll
      for (int kf = 0; kf < 4; ++kf)
        bwx[g][kf] = *(const bf16x8*)(wsp + ((size_t)(g * 4 + kf) * 256 + cs * 64 + l) * 8);
#pragma unroll
      for (int kf = 0; kf < 2; ++kf)
        bwh[g][kf] = *(const bf16x8*)(wsp + ((size_t)(16 + g * 2 + kf) * 256 + cs * 64 + l) * 8);
      bias4[g] = bg[g * 64 + cs * 16 + row16];
    }
  }
  if (tid < 256) ((uint64_t*)(pool + HB0))[tid] = 0ull;   // h_{-1} = 0 (parity 0)

  // ---- pre-periods: cvt xs(0) -> bxs0, cvt xs(1) -> bxs1 ----
#define PRE(TSTEP, VMC) \
  if (w >= 4) { \
    asm volatile("s_waitcnt vmcnt(" #VMC ")" ::: "memory"); \
    const char* xb = pool + (TSTEP) * 8192; \
    float4 ya = *(const float4*)(xb + offxA); \
    float4 yb = *(const float4*)(xb + offxB); \
    bf16x8 bv = cvt8(ya, yb); \
    *(bf16x8*)(pool + BX0 + (TSTEP) * 4096 + row16 * 256 + \
               (((pw * 4 + kg) << 4) ^ swz)) = bv; \
  } \
  asm volatile("s_waitcnt lgkmcnt(0)\n\ts_barrier" ::: "memory");

  PRE(0, 10)
  PRE(1, 8)
#undef PRE

  // ---- main loop: 256 periods, unrolled x8 (all ring indices & W1 bufs are static) ----
#pragma unroll 1
  for (int pp = 0; pp < TT; pp += 8) {
    PERIOD(pp + 0, 0, cwa0, cwb0, cwa1, cwb1)
    PERIOD(pp + 1, 1, cwa1, cwb1, cwa0, cwb0)
    PERIOD(pp + 2, 2, cwa0, cwb0, cwa1, cwb1)
    PERIOD(pp + 3, 3, cwa1, cwb1, cwa0, cwb0)
    PERIOD(pp + 4, 4, cwa0, cwb0, cwa1, cwb1)
    PERIOD(pp + 5, 5, cwa1, cwb1, cwa0, cwb0)
    PERIOD(pp + 6, 6, cwa0, cwb0, cwa1, cwb1)
    PERIOD(pp + 7, 7, cwa1, cwb1, cwa0, cwb0)
  }

  __syncthreads();   // full drain (incl. in-flight DMAs) before aliasing xs as W2

  // stage W2 into the dead xs region
  {
    float* w2l = (float*)pool;
    for (int i = tid; i < 4096; i += 512) w2l[i] = W2[i];
  }

  if (w < 4) {
    // final c/h outputs (h(255) in parity-0 hbuf; cacc in regs)
    const char* hb = pool + HB0;
#pragma unroll
    for (int jj = 0; jj < 4; ++jj) {
      const int row = kg * 4 + jj;
      out[C_OFF + (size_t)(b0 + row) * HH + kcol] = cacc[jj];
      uint32_t hu = *(const uint16_t*)(hb + row * 128 +
                    (((kcol >> 3) << 4) ^ ((row & 7) << 4)) + (kcol & 7) * 2);
      union { uint32_t u; float f; } cv_; cv_.u = hu << 16;
      out[H_OFF + (size_t)(b0 + row) * HH + kcol] = cv_.f;
    }
  } else {
    // W1 tail (converters hold wacc): wacc += h(255) x W1block(255)
    // (last period U=7 loaded block 255 into cw*0)
    const char* hb = pool + HB0;
    bf16x8 at0 = *(const bf16x8*)(hb + row16 * 128 + (((0 + kg) << 4) ^ swz));
    bf16x8 at1 = *(const bf16x8*)(hb + row16 * 128 + (((4 + kg) << 4) ^ swz));
    wacc = MFMA16(at0, cwa0, wacc, 0, 0, 0);
    wacc = MFMA16(at1, cwb0, wacc, 0, 0, 0);
    const float bv = b1[kcol];
    float* mlpa = (float*)(pool + MA0);
#pragma unroll
    for (int jj = 0; jj < 4; ++jj)
      mlpa[(kg * 4 + jj) * 65 + kcol] = fmaxf(wacc[jj] + bv, 0.f);
  }
  __syncthreads();
  {  // MLP layer 2: 16x64 outputs, MA0 -> MB0
    const float* mlpa = (const float*)(pool + MA0);
    const float* w2l  = (const float*)pool;
    float* mlpb = (float*)(pool + MB0);
    const int b = tid >> 5, j0 = tid & 31;
    float s0 = b2[j0], s1 = b2[j0 + 32];
#pragma unroll 8
    for (int k = 0; k < 64; ++k) {
      const float av = mlpa[b * 65 + k];
      s0 += av * w2l[k * 64 + j0];
      s1 += av * w2l[k * 64 + j0 + 32];
    }
    mlpb[b * 65 + j0]      = fmaxf(s0, 0.f);
    mlpb[b * 65 + j0 + 32] = fmaxf(s1, 0.f);
  }
  __syncthreads();
  if (tid < 128) {  // MLP layer 3: 16x8 outputs
    const float* mlpb = (const float*)(pool + MB0);
    const int b = tid >> 3, jj = tid & 7;
    float s = b3[jj];
#pragma unroll 8
    for (int k = 0; k < 64; ++k) s += mlpb[b * 65 + k] * W3[(size_t)k * 8 + jj];
    out[(size_t)(b0 + b) * 8 + jj] = s;
  }
}

// ---------------- fallback (R2 kernel, used only if ws_size too small) ----------------
__global__ __launch_bounds__(256, 1) void actor_fused_fb(
    const float* __restrict__ x,  const float* __restrict__ pa,
    const float* __restrict__ Wx, const float* __restrict__ Wh,
    const float* __restrict__ bg, const float* __restrict__ W1,
    const float* __restrict__ b1, const float* __restrict__ W2,
    const float* __restrict__ b2, const float* __restrict__ W3,
    const float* __restrict__ b3, float* __restrict__ out)
{
  __shared__ __align__(16) uint16_t xs_lds[2][BB * 128];
  __shared__ __align__(16) uint16_t h_lds[2][BB * HH];
  __shared__ float w2_lds[64 * 64];
  __shared__ float mlp_a[BB * 65];
  __shared__ float mlp_b[BB * 65];

  const int tid = threadIdx.x, w = tid >> 6, l = tid & 63;
  const int row16 = l & 15, kg = l >> 4;
  const int b0 = blockIdx.x * BB, swz = (row16 & 7) << 4;

  bf16x8 bwx[4][4], bwh[4][2];
  float bias4[4];
#pragma unroll
  for (int g = 0; g < 4; ++g) {
    const int col = g * 64 + w * 16 + row16;
    bias4[g] = bg[col];
#pragma unroll
    for (int kf = 0; kf < 4; ++kf)
#pragma unroll
      for (int j = 0; j < 8; ++j)
        bwx[g][kf][j] = (short)f2bf(Wx[(size_t)(kf * 32 + kg * 8 + j) * GG + col]);
#pragma unroll
    for (int kf = 0; kf < 2; ++kf)
#pragma unroll
      for (int j = 0; j < 8; ++j)
        bwh[g][kf][j] = (short)f2bf(Wh[(size_t)(kf * 32 + kg * 8 + j) * GG + col]);
  }
  for (int i = tid; i < 64 * 64; i += 256) w2_lds[i] = W2[i];
  reinterpret_cast<uint64_t*>(&h_lds[0][0])[tid] = 0ull;

  const int srow = tid >> 4, li = tid & 15;
  const int st_byte = srow * 256 + ((li << 4) ^ ((srow & 7) << 4));
  {
    const size_t base = (size_t)(b0 + srow) * TT + 0;
    float4 fa, fb;
    if (li < 15) { fa = *(const float4*)(x + base * FF + li * 8);
                   fb = *(const float4*)(x + base * FF + li * 8 + 4); }
    else         { fa = *(const float4*)(x + base * FF + 120);
                   fb = *(const float4*)(pa + base * 4); }
    uint4 pk;
    pk.x = (uint32_t)f2bf(fa.x) | ((uint32_t)f2bf(fa.y) << 16);
    pk.y = (uint32_t)f2bf(fa.z) | ((uint32_t)f2bf(fa.w) << 16);
    pk.z = (uint32_t)f2bf(fb.x) | ((uint32_t)f2bf(fb.y) << 16);
    pk.w = (uint32_t)f2bf(fb.z) | ((uint32_t)f2bf(fb.w) << 16);
    *(uint4*)((char*)&xs_lds[0][0] + st_byte) = pk;
  }
  float4 pfa, pfb;
  {
    const size_t base = (size_t)(b0 + srow) * TT + 1;
    if (li < 15) { pfa = *(const float4*)(x + base * FF + li * 8);
                   pfb = *(const float4*)(x + base * FF + li * 8 + 4); }
    else         { pfa = *(const float4*)(x + base * FF + 120);
                   pfb = *(const float4*)(pa + base * 4); }
  }
  __syncthreads();

  f32x4 cacc = {0.f, 0.f, 0.f, 0.f};
  f32x4 wacc = {0.f, 0.f, 0.f, 0.f};
  int cur = 0;

  for (int t = 0; t < TT; ++t) {
    {
      uint4 pk;
      pk.x = (uint32_t)f2bf(pfa.x) | ((uint32_t)f2bf(pfa.y) << 16);
      pk.y = (uint32_t)f2bf(pfa.z) | ((uint32_t)f2bf(pfa.w) << 16);
      pk.z = (uint32_t)f2bf(pfb.x) | ((uint32_t)f2bf(pfb.y) << 16);
      pk.w = (uint32_t)f2bf(pfb.z) | ((uint32_t)f2bf(pfb.w) << 16);
      *(uint4*)((char*)&xs_lds[cur ^ 1][0] + st_byte) = pk;
    }
    {
      const int tp = (t + 2 < TT) ? (t + 2) : (TT - 1);
      const size_t base = (size_t)(b0 + srow) * TT + tp;
      if (li < 15) { pfa = *(const float4*)(x + base * FF + li * 8);
                     pfb = *(const float4*)(x + base * FF + li * 8 + 4); }
      else         { pfa = *(const float4*)(x + base * FF + 120);
                     pfb = *(const float4*)(pa + base * 4); }
    }
    bf16x8 bw1a, bw1b;
    if (t > 0) {
      const size_t r0 = (size_t)(t - 1) * 64 + kg * 8;
      const int c1w = w * 16 + row16;
#pragma unroll
      for (int j = 0; j < 8; ++j) {
        bw1a[j] = (short)f2bf(W1[(r0 + j) * 64 + c1w]);
        bw1b[j] = (short)f2bf(W1[(r0 + 32 + j) * 64 + c1w]);
      }
    }
    const char* xb = (const char*)&xs_lds[cur][0];
    const char* hb = (const char*)&h_lds[cur][0];
    bf16x8 ax0 = *(const bf16x8*)(xb + row16 * 256 + (((0 * 4 + kg) << 4) ^ swz));
    bf16x8 ax1 = *(const bf16x8*)(xb + row16 * 256 + (((1 * 4 + kg) << 4) ^ swz));
    bf16x8 ax2 = *(const bf16x8*)(xb + row16 * 256 + (((2 * 4 + kg) << 4) ^ swz));
    bf16x8 ax3 = *(const bf16x8*)(xb + row16 * 256 + (((3 * 4 + kg) << 4) ^ swz));
    bf16x8 ah0 = *(const bf16x8*)(hb + row16 * 128 + (((0 + kg) << 4) ^ swz));
    bf16x8 ah1 = *(const bf16x8*)(hb + row16 * 128 + (((4 + kg) << 4) ^ swz));

    f32x4 g0 = {bias4[0], bias4[0], bias4[0], bias4[0]};
    f32x4 g1 = {bias4[1], bias4[1], bias4[1], bias4[1]};
    f32x4 g2 = {bias4[2], bias4[2], bias4[2], bias4[2]};
    f32x4 g3 = {bias4[3], bias4[3], bias4[3], bias4[3]};
    g0 = MFMA16(ax0, bwx[0][0], g0, 0, 0, 0);
    g1 = MFMA16(ax0, bwx[1][0], g1, 0, 0, 0);
    g2 = MFMA16(ax0, bwx[2][0], g2, 0, 0, 0);
    g3 = MFMA16(ax0, bwx[3][0], g3, 0, 0, 0);
    g0 = MFMA16(ax1, bwx[0][1], g0, 0, 0, 0);
    g1 = MFMA16(ax1, bwx[1][1], g1, 0, 0, 0);
    g2 = MFMA16(ax1, bwx[2][1], g2, 0, 0, 0);
    g3 = MFMA16(ax1, bwx[3][1], g3, 0, 0, 0);
    g0 = MFMA16(ax2, bwx[0][2], g0, 0, 0, 0);
    g1 = MFMA16(ax2, bwx[1][2], g1, 0, 0, 0);
    g2 = MFMA16(ax2, bwx[2][2], g2, 0, 0, 0);
    g3 = MFMA16(ax2, bwx[3][2], g3, 0, 0, 0);
    g0 = MFMA16(ax3, bwx[0][3], g0, 0, 0, 0);
    g1 = MFMA16(ax3, bwx[1][3], g1, 0, 0, 0);
    g2 = MFMA16(ax3, bwx[2][3], g2, 0, 0, 0);
    g3 = MFMA16(ax3, bwx[3][3], g3, 0, 0, 0);
    g0 = MFMA16(ah0, bwh[0][0], g0, 0, 0, 0);
    g1 = MFMA16(ah0, bwh[1][0], g1, 0, 0, 0);
    g2 = MFMA16(ah0, bwh[2][0], g2, 0, 0, 0);
    g3 = MFMA16(ah0, bwh[3][0], g3, 0, 0, 0);
    g0 = MFMA16(ah1, bwh[0][1], g0, 0, 0, 0);
    g1 = MFMA16(ah1, bwh[1][1], g1, 0, 0, 0);
    g2 = MFMA16(ah1, bwh[2][1], g2, 0, 0, 0);
    g3 = MFMA16(ah1, bwh[3][1], g3, 0, 0, 0);
    if (t > 0) {
      wacc = MFMA16(ah0, bw1a, wacc, 0, 0, 0);
      wacc = MFMA16(ah1, bw1b, wacc, 0, 0, 0);
    }
    const int kcol = w * 16 + row16;
#pragma unroll
    for (int jj = 0; jj < 4; ++jj) {
      float i_ = fsig(g0[jj]);
      float f_ = fsig(g1[jj]);
      float gv = ftanh(g2[jj]);
      float o_ = fsig(g3[jj]);
      float cn = f_ * cacc[jj] + i_ * gv;
      cacc[jj] = cn;
      float hv = o_ * ftanh(cn);
      const int row = kg * 4 + jj;
      *(uint16_t*)((char*)&h_lds[cur ^ 1][0] + row * 128 +
                   (((kcol >> 3) << 4) ^ ((row & 7) << 4)) + (kcol & 7) * 2) = f2bf(hv);
      if (t == TT - 1) {
        out[C_OFF + (size_t)(b0 + row) * HH + kcol] = cn;
        out[H_OFF + (size_t)(b0 + row) * HH + kcol] = hv;
      }
    }
    __syncthreads();
    cur ^= 1;
  }
  {
    const char* hb = (const char*)&h_lds[cur][0];
    bf16x8 at0 = *(const bf16x8*)(hb + row16 * 128 + (((0 + kg) << 4) ^ swz));
    bf16x8 at1 = *(const bf16x8*)(hb + row16 * 128 + (((4 + kg) << 4) ^ swz));
    bf16x8 bw1a, bw1b;
    const size_t r0 = (size_t)(TT - 1) * 64 + kg * 8;
    const int c1w = w * 16 + row16;
#pragma unroll
    for (int j = 0; j < 8; ++j) {
      bw1a[j] = (short)f2bf(W1[(r0 + j) * 64 + c1w]);
      bw1b[j] = (short)f2bf(W1[(r0 + 32 + j) * 64 + c1w]);
    }
    wacc = MFMA16(at0, bw1a, wacc, 0, 0, 0);
    wacc = MFMA16(at1, bw1b, wacc, 0, 0, 0);
  }
  {
    const int kcol = w * 16 + row16;
    const float bv = b1[kcol];
#pragma unroll
    for (int jj = 0; jj < 4; ++jj)
      mlp_a[(kg * 4 + jj) * 65 + kcol] = fmaxf(wacc[jj] + bv, 0.f);
  }
  __syncthreads();
  {
    const int b = tid >> 4, j0 = tid & 15;
    float s0 = b2[j0], s1 = b2[j0 + 16], s2 = b2[j0 + 32], s3 = b2[j0 + 48];
#pragma unroll 8
    for (int k = 0; k < 64; ++k) {
      const float av = mlp_a[b * 65 + k];
      s0 += av * w2_lds[k * 64 + j0];
      s1 += av * w2_lds[k * 64 + j0 + 16];
      s2 += av * w2_lds[k * 64 + j0 + 32];
      s3 += av * w2_lds[k * 64 + j0 + 48];
    }
    mlp_b[b * 65 + j0]      = fmaxf(s0, 0.f);
    mlp_b[b * 65 + j0 + 16] = fmaxf(s1, 0.f);
    mlp_b[b * 65 + j0 + 32] = fmaxf(s2, 0.f);
    mlp_b[b * 65 + j0 + 48] = fmaxf(s3, 0.f);
  }
  __syncthreads();
  if (tid < 128) {
    const int b = tid >> 3, jj = tid & 7;
    float s = b3[jj];
#pragma unroll 8
    for (int k = 0; k < 64; ++k) s += mlp_b[b * 65 + k] * W3[(size_t)k * 8 + jj];
    out[(size_t)(b0 + b) * 8 + jj] = s;
  }
}

extern "C" void kernel_launch(void* const* d_in, const int* in_sizes, int n_in,
                              void* d_out, int out_size, void* d_ws, size_t ws_size,
                              hipStream_t stream) {
  const float* x  = (const float*)d_in[0];
  const float* pa = (const float*)d_in[1];
  const float* Wx = (const float*)d_in[2];
  const float* Wh = (const float*)d_in[3];
  const float* bg = (const float*)d_in[4];
  const float* W1 = (const float*)d_in[5];
  const float* b1 = (const float*)d_in[6];
  const float* W2 = (const float*)d_in[7];
  const float* b2 = (const float*)d_in[8];
  const float* W3 = (const float*)d_in[9];
  const float* b3 = (const float*)d_in[10];
  (void)in_sizes; (void)n_in; (void)out_size;

  if (ws_size >= WS_NEED) {
    uint16_t* wsp = (uint16_t*)d_ws;
    pack_weights<<<dim3(536), dim3(256), 0, stream>>>(Wx, Wh, W1, wsp);
    actor_sx<<<dim3(Bsz / BB), dim3(512), 0, stream>>>(
        x, pa, bg, wsp, b1, W2, b2, W3, b3, (float*)d_out);
  } else {
    actor_fused_fb<<<dim3(Bsz / BB), dim3(256), 0, stream>>>(
        x, pa, Wx, Wh, bg, W1, b1, W2, b2, W3, b3, (float*)d_out);
  }
}